// Round 10
// baseline (207.994 us; speedup 1.0000x reference)
//
#include <hip/hip_runtime.h>
#include <hip/hip_fp16.h>
#include <math.h>

#define S 256
#define A 180
#define B 4
#define PMAX 316           // max row stride in halves; 257*316*2 = 162,424 B LDS
#define NROWS 257          // 256 image rows + 1 zero pad row

// Kernel 1: inscribed-circle mask (dx^2+dy^2 <= 128^2 == sqrt<=128) + fp32->fp16.
__global__ void radon_mask_f16(const float* __restrict__ in, __half* __restrict__ out) {
    int idx = blockIdx.x * 256 + threadIdx.x;    // 0 .. B*S*S-1
    int p = idx & (S * S - 1);
    int y = p >> 8;
    int x = p & 255;
    int dx = x - 128, dy = y - 128;
    float v = in[idx];
    v = (dx * dx + dy * dy <= 16384) ? v : 0.0f;
    out[idx] = __float2half(v);
}

// Kernel 2: R8 structure (69.6 us proven: R5 base + per-angle runtime stride P)
// + ONE change: interior bilinear math in mixed precision. f16 corner diffs
// (__hsub) feed f32 FMAs via (float) casts -> LLVM forms v_fma_mix_f32,
// eliminating the 4 v_cvt_f32_f16 per tap (~20% of interior VALU).
__global__ __launch_bounds__(1024, 1) void radon_lds_kernel(const __half* __restrict__ img,
                                                            float* __restrict__ out) {
    __shared__ __half lds[NROWS * PMAX];         // 162,424 B

    const int a = blockIdx.x;   // angle
    const int b = blockIdx.y;   // batch
    const int tid = threadIdx.x;

    float ang = (float)a * (float)(M_PI / 179.0);
    float sn, cs;
    sincosf(ang, &sn, &cs);

    // per-angle stride: lane half-stride = P*cs - sn; want dword stride ~odd
    int P = 258;
    {
        float best = 1e9f;
        for (int cand = 258; cand <= PMAX; cand += 2) {
            float sd = 0.5f * fabsf((float)cand * cs - sn);   // dwords/lane
            float m = sd - 2.0f * floorf(sd * 0.5f);          // mod 2
            float score = fabsf(m - 1.0f);                    // 0 = odd = free
            if (score < best) { best = score; P = cand; }
        }
    }
    const int Ph = P >> 1;

    // ---- stage image (65536 halves = 32768 dwords), coalesced ----
    const uint* __restrict__ src = (const uint*)(img + (size_t)b * (S * S));
    uint* l32 = (uint*)lds;
#pragma unroll
    for (int k = 0; k < 32; ++k) {
        int p = k * 1024 + tid;
        int y = p >> 7;            // 128 dwords per source row
        int xp = p & 127;
        l32[y * Ph + xp] = src[p];
    }
    // zero pad cols 256/257 of rows 0..255 and all of pad row 256 (dwords 0..128)
    if (tid < 256) {
        l32[tid * Ph + 128] = 0u;
    } else if (tid < 256 + 129) {
        l32[256 * Ph + (tid - 256)] = 0u;
    }
    __syncthreads();

    const int j = tid & 255;
    const int iq = tid >> 8;

    const float ry = (float)j - 127.5f;
    const float bx = fmaf(-sn, ry, 127.5f);
    const float by = fmaf(cs, ry, 127.5f);
    const float ry2 = ry * ry;

    // disk trim: keep i with rx^2 + ry^2 <= 16934 (~130.13^2 > provable 130.122)
    float h = sqrtf(16934.0f - ry2);
    int ilo = (int)ceilf(127.5f - h);
    int ihi = (int)floorf(127.5f + h) + 1;
    ilo = max(ilo, iq * 64);
    ihi = min(ihi, iq * 64 + 64);
    ilo = max(ilo, 0);
    ihi = min(ihi, S);

    const float FAST2 = 126.5f * 126.5f;
    float acc = 0.0f;

#pragma unroll 4
    for (int i = ilo; i < ihi; ++i) {
        float rx = (float)i - 127.5f;
        float px = fmaf(cs, rx, bx);
        float py = fmaf(sn, rx, by);

        float x0f = floorf(px);
        float y0f = floorf(py);
        float wx = px - x0f;
        float wy = py - y0f;
        int x0 = (int)x0f;
        int y0 = (int)y0f;

        float d2 = fmaf(rx, rx, ry2);
        if (d2 <= FAST2) {
            // interior: all corners in-bounds; mixed-precision lerp
            const __half* p0 = &lds[y0 * P + x0];
            __half v00 = p0[0];
            __half v10 = p0[1];
            __half v01 = p0[P];
            __half v11 = p0[P + 1];
            __half d0 = __hsub(v10, v00);
            __half d1 = __hsub(v11, v01);
            float r0 = fmaf(wx, __half2float(d0), __half2float(v00));
            float r1 = fmaf(wx, __half2float(d1), __half2float(v01));
            acc = fmaf(wy, r1 - r0, acc + r0);
        } else {
            // rim: zero weights of OOB corners, clamp each index independently
            float ux = 1.0f - wx;
            float uy = 1.0f - wy;
            float w00 = ux * uy;
            float w10 = wx * uy;
            float w01 = ux * wy;
            float w11 = wx * wy;
            bool vx0 = ((unsigned)x0 < 256u);
            bool vx1 = ((unsigned)(x0 + 1) < 256u);
            bool vy0 = ((unsigned)y0 < 256u);
            bool vy1 = ((unsigned)(y0 + 1) < 256u);
            w00 = (vx0 && vy0) ? w00 : 0.0f;
            w10 = (vx1 && vy0) ? w10 : 0.0f;
            w01 = (vx0 && vy1) ? w01 : 0.0f;
            w11 = (vx1 && vy1) ? w11 : 0.0f;
            int x0r = min(max(x0, 0), 255);
            int x1r = min(max(x0 + 1, 0), 256);    // col 256 = zeroed pad
            int y0r = min(max(y0, 0), 255);
            int y1r = min(max(y0 + 1, 0), 256);    // row 256 = zeroed pad
            float v00 = __half2float(lds[y0r * P + x0r]);
            float v10 = __half2float(lds[y0r * P + x1r]);
            float v01 = __half2float(lds[y1r * P + x0r]);
            float v11 = __half2float(lds[y1r * P + x1r]);
            acc = fmaf(w00, v00, fmaf(w10, v10, fmaf(w01, v01, fmaf(w11, v11, acc))));
        }
    }

    // ---- reduce the 4 i-quarters per j (reuse LDS after barrier) ----
    __syncthreads();
    float* red = (float*)lds;
    red[tid] = acc;
    __syncthreads();
    if (iq == 0) {
        float r = red[j] + red[j + 256] + red[j + 512] + red[j + 768];
        out[((size_t)b * A + a) * S + j] = r;
    }
}

extern "C" void kernel_launch(void* const* d_in, const int* in_sizes, int n_in,
                              void* d_out, int out_size, void* d_ws, size_t ws_size,
                              hipStream_t stream) {
    const float* x = (const float*)d_in[0];
    float* out = (float*)d_out;
    __half* masked = (__half*)d_ws;  // B*S*S halves = 512 KiB

    radon_mask_f16<<<dim3((B * S * S) / 256), dim3(256), 0, stream>>>(x, masked);
    radon_lds_kernel<<<dim3(A, B), dim3(1024), 0, stream>>>(masked, out);
}

// Round 11
// 121.880 us; speedup vs baseline: 1.7066x; 1.7066x over previous
//
#include <hip/hip_runtime.h>
#include <hip/hip_fp16.h>
#include <math.h>

#define S 256
#define A 180
#define B 4
#define PMAX 316           // max row stride in halves; 257*316*2 = 162,424 B LDS
#define NROWS 257          // 256 image rows + 1 zero pad row

// Kernel 1: inscribed-circle mask (dx^2+dy^2 <= 128^2 == sqrt<=128) + fp32->fp16.
__global__ void radon_mask_f16(const float* __restrict__ in, __half* __restrict__ out) {
    int idx = blockIdx.x * 256 + threadIdx.x;    // 0 .. B*S*S-1
    int p = idx & (S * S - 1);
    int y = p >> 8;
    int x = p & 255;
    int dx = x - 128, dy = y - 128;
    float v = in[idx];
    v = (dx * dx + dy * dy <= 16384) ? v : 0.0f;
    out[idx] = __float2half(v);
}

// Kernel 2: R8 structure (69.6 us proven). Two VALU-thinning changes only:
// (1) per-angle stride P computed by thread 0 and broadcast via LDS (the
//     30-candidate search was ~11% of every thread's VALU);
// (2) incremental rx/px/py stepping in the tap loop (rx exact: integer-valued
//     fp32 increments; px/py drift <=1e-4 px, bilinear is continuous).
// Loads / rim path / staging byte-identical to R8 (R10 showed f16-typed ALU
// triggers d16-load codegen that serializes the corner loads: 69.6->161 us).
__global__ __launch_bounds__(1024, 1) void radon_lds_kernel(const __half* __restrict__ img,
                                                            float* __restrict__ out) {
    __shared__ __half lds[NROWS * PMAX];         // 162,424 B
    __shared__ int sP;

    const int a = blockIdx.x;   // angle
    const int b = blockIdx.y;   // batch
    const int tid = threadIdx.x;

    float ang = (float)a * (float)(M_PI / 179.0);
    float sn, cs;
    sincosf(ang, &sn, &cs);

    // per-angle stride: lane half-stride = P*cs - sn; want dword stride ~odd.
    // Thread 0 only -- broadcast (identical result to R8's per-thread search).
    if (tid == 0) {
        int P = 258;
        float best = 1e9f;
        for (int cand = 258; cand <= PMAX; cand += 2) {
            float sd = 0.5f * fabsf((float)cand * cs - sn);   // dwords/lane
            float m = sd - 2.0f * floorf(sd * 0.5f);          // mod 2
            float score = fabsf(m - 1.0f);                    // 0 = odd = free
            if (score < best) { best = score; P = cand; }
        }
        sP = P;
    }
    __syncthreads();
    const int P = sP;
    const int Ph = P >> 1;

    // ---- stage image (65536 halves = 32768 dwords), coalesced ----
    const uint* __restrict__ src = (const uint*)(img + (size_t)b * (S * S));
    uint* l32 = (uint*)lds;
#pragma unroll
    for (int k = 0; k < 32; ++k) {
        int p = k * 1024 + tid;
        int y = p >> 7;            // 128 dwords per source row
        int xp = p & 127;
        l32[y * Ph + xp] = src[p];
    }
    // zero pad cols 256/257 of rows 0..255 and all of pad row 256 (dwords 0..128)
    if (tid < 256) {
        l32[tid * Ph + 128] = 0u;
    } else if (tid < 256 + 129) {
        l32[256 * Ph + (tid - 256)] = 0u;
    }
    __syncthreads();

    const int j = tid & 255;
    const int iq = tid >> 8;

    const float ry = (float)j - 127.5f;
    const float bx = fmaf(-sn, ry, 127.5f);
    const float by = fmaf(cs, ry, 127.5f);
    const float ry2 = ry * ry;

    // disk trim: keep i with rx^2 + ry^2 <= 16934 (~130.13^2 > provable 130.122)
    float h = sqrtf(16934.0f - ry2);
    int ilo = (int)ceilf(127.5f - h);
    int ihi = (int)floorf(127.5f + h) + 1;
    ilo = max(ilo, iq * 64);
    ihi = min(ihi, iq * 64 + 64);
    ilo = max(ilo, 0);
    ihi = min(ihi, S);

    const float FAST2 = 126.5f * 126.5f;
    float acc = 0.0f;

    // incremental ray state: rx exact (integer-valued fp32 steps)
    float rx = (float)ilo - 127.5f;
    float px = fmaf(cs, rx, bx);
    float py = fmaf(sn, rx, by);

#pragma unroll 4
    for (int i = ilo; i < ihi; ++i) {
        float x0f = floorf(px);
        float y0f = floorf(py);
        float wx = px - x0f;
        float wy = py - y0f;
        int x0 = (int)x0f;
        int y0 = (int)y0f;

        float d2 = fmaf(rx, rx, ry2);
        if (d2 <= FAST2) {
            // interior: px,py in [1,254] -> all corners in-bounds
            float ux = 1.0f - wx;
            float uy = 1.0f - wy;
            float w00 = ux * uy;
            float w10 = wx * uy;
            float w01 = ux * wy;
            float w11 = wx * wy;
            const __half* p0 = &lds[y0 * P + x0];
            float v00 = __half2float(p0[0]);
            float v10 = __half2float(p0[1]);
            float v01 = __half2float(p0[P]);
            float v11 = __half2float(p0[P + 1]);
            acc = fmaf(w00, v00, fmaf(w10, v10, fmaf(w01, v01, fmaf(w11, v11, acc))));
        } else {
            // rim: zero weights of OOB corners, clamp each index independently
            float ux = 1.0f - wx;
            float uy = 1.0f - wy;
            float w00 = ux * uy;
            float w10 = wx * uy;
            float w01 = ux * wy;
            float w11 = wx * wy;
            bool vx0 = ((unsigned)x0 < 256u);
            bool vx1 = ((unsigned)(x0 + 1) < 256u);
            bool vy0 = ((unsigned)y0 < 256u);
            bool vy1 = ((unsigned)(y0 + 1) < 256u);
            w00 = (vx0 && vy0) ? w00 : 0.0f;
            w10 = (vx1 && vy0) ? w10 : 0.0f;
            w01 = (vx0 && vy1) ? w01 : 0.0f;
            w11 = (vx1 && vy1) ? w11 : 0.0f;
            int x0r = min(max(x0, 0), 255);
            int x1r = min(max(x0 + 1, 0), 256);    // col 256 = zeroed pad
            int y0r = min(max(y0, 0), 255);
            int y1r = min(max(y0 + 1, 0), 256);    // row 256 = zeroed pad
            float v00 = __half2float(lds[y0r * P + x0r]);
            float v10 = __half2float(lds[y0r * P + x1r]);
            float v01 = __half2float(lds[y1r * P + x0r]);
            float v11 = __half2float(lds[y1r * P + x1r]);
            acc = fmaf(w00, v00, fmaf(w10, v10, fmaf(w01, v01, fmaf(w11, v11, acc))));
        }

        rx += 1.0f;
        px += cs;
        py += sn;
    }

    // ---- reduce the 4 i-quarters per j (reuse LDS after barrier) ----
    __syncthreads();
    float* red = (float*)lds;
    red[tid] = acc;
    __syncthreads();
    if (iq == 0) {
        float r = red[j] + red[j + 256] + red[j + 512] + red[j + 768];
        out[((size_t)b * A + a) * S + j] = r;
    }
}

extern "C" void kernel_launch(void* const* d_in, const int* in_sizes, int n_in,
                              void* d_out, int out_size, void* d_ws, size_t ws_size,
                              hipStream_t stream) {
    const float* x = (const float*)d_in[0];
    float* out = (float*)d_out;
    __half* masked = (__half*)d_ws;  // B*S*S halves = 512 KiB

    radon_mask_f16<<<dim3((B * S * S) / 256), dim3(256), 0, stream>>>(x, masked);
    radon_lds_kernel<<<dim3(A, B), dim3(1024), 0, stream>>>(masked, out);
}